// Round 3
// baseline (480.955 us; speedup 1.0000x reference)
//
#include <hip/hip_runtime.h>

typedef unsigned short u16;
typedef unsigned int   u32;
typedef short bf16x8 __attribute__((ext_vector_type(8)));
typedef float f32x4 __attribute__((ext_vector_type(4)));

#define APN   22
#define NBK   8            // nucleotides per k_fused block
#define AB    176          // atoms per block = 22*8 = 11 m-tiles of 16

__device__ __forceinline__ float bflo(u32 u){ return __uint_as_float(u << 16); }
__device__ __forceinline__ float bfhi(u32 u){ return __uint_as_float(u & 0xffff0000u); }
__device__ __forceinline__ u16 f2bf(float f){
  u32 u = __float_as_uint(f);
  u32 r = u + 0x7fffu + ((u >> 16) & 1u);
  return (u16)(r >> 16);
}
__device__ __forceinline__ u32 pack2(float a, float b){
  return (u32)f2bf(a) | ((u32)f2bf(b) << 16);
}
__device__ __forceinline__ u32 cvtpk(float lo, float hi){
  u32 d;
  asm volatile("v_cvt_pk_bf16_f32 %0, %1, %2" : "=v"(d) : "v"(lo), "v"(hi));
  return d;
}
__device__ __forceinline__ float wave_sum(float v){
  #pragma unroll
  for (int off = 32; off; off >>= 1) v += __shfl_xor(v, off, 64);
  return v;
}
__device__ __forceinline__ float fast_tanh(float x){
  float t = __expf(-2.f * x);
  return 2.f * __builtin_amdgcn_rcpf(1.f + t) - 1.f;
}
__device__ __forceinline__ float silu_f(float x){
  return x * __builtin_amdgcn_rcpf(1.f + __expf(-x));
}
// async global->LDS, 16B per lane; LDS dest = wave-uniform base + lane*16 (linear)
__device__ __forceinline__ void gl_lds16(const float* g, const void* l){
  __builtin_amdgcn_global_load_lds(
      (const __attribute__((address_space(1))) void*)g,
      (__attribute__((address_space(3))) void*)l, 16, 0, 0);
}

// ---- prep 1: swizzle attn_W1 (fp32 [138][128]) into MFMA B-fragment layout, bf16 ----
// k-order remap: k' 0..127 -> W1 row 10+k' (emb part), 128..137 -> row k'-128 (phys), 138..159 -> 0
// layout: bfrag[ks(5)][t(8)][lane(64)][j(8)] bf16; B[k=ks*32+(lane>>4)*8+j][n=t*16+(lane&15)]
__global__ void k_prep_w1(const float* __restrict__ W1, u32* __restrict__ bfrag32)
{
  const int b = blockIdx.x;          // 0..39 = ks*8 + t
  const int ks = b >> 3, t = b & 7;
  const int e0 = threadIdx.x * 2;    // element pair
  const int lane = e0 >> 3, j = e0 & 7;
  const int n = t * 16 + (lane & 15);
  float v[2];
  #pragma unroll
  for (int i = 0; i < 2; ++i) {
    int kp = ks * 32 + ((lane >> 4) * 8) + j + i;
    float val = 0.f;
    if (kp < 128)       val = W1[(size_t)(10 + kp) * 128 + n];
    else if (kp < 138)  val = W1[(size_t)(kp - 128) * 128 + n];
    v[i] = val;
  }
  bfrag32[((size_t)(b * 64 + lane)) * 4 + (j >> 1)] = pack2(v[0], v[1]);
}

// ---- prep 2: pack comb/rot/tr W1 weights into MFMA B-fragment layout, bf16 ----
__global__ void k_prep_frag3(const float* __restrict__ combW, const float* __restrict__ rotW1,
                             const float* __restrict__ trW1,
                             u32* __restrict__ combF, u32* __restrict__ rotF, u32* __restrict__ trF)
{
  const int b = blockIdx.x;
  const float* W; u32* outp; int rel;
  if (b < 96)       { W = combW; outp = combF; rel = b; }
  else if (b < 128) { W = rotW1; outp = rotF;  rel = b - 96; }
  else              { W = trW1;  outp = trF;   rel = b - 128; }
  const int ks = rel >> 3, t = rel & 7;
  const int e0 = threadIdx.x * 2;
  const int lane = e0 >> 3, j = e0 & 7;        // j in {0,2,4,6}
  const int n = t * 16 + (lane & 15);
  const int k = ks * 32 + ((lane >> 4) * 8) + j;
  outp[((size_t)(rel * 64 + lane)) * 4 + (j >> 1)] =
      pack2(W[(size_t)k * 128 + n], W[(size_t)(k + 1) * 128 + n]);
}

// ---- fused K1+K2 v3: K-sliced global_load_lds streaming + col-split MFMA ----
// eslice[buf][176 rows][32 f32 cols], row = 8 float4-groups; stage stores global group g
// at LDS slot g^(row&7) (both-sides XOR swizzle -> conflict-free-ish b128 reads).
// Pooled phase re-reads emb from global (L2-hot) in fp32.
__global__ __launch_bounds__(256, 3) void k_fused(
    const float* __restrict__ phys, const float* __restrict__ emb,
    const float* __restrict__ b1, const float* __restrict__ W2,
    const uint4* __restrict__ bfragG,       // [5][8][64] uint4
    float* __restrict__ pooled, int A, int N)
{
  __shared__ float4 eslice[2][1408];        // 45,056 B (2 x 176 x 32 f32)
  __shared__ float s_part[4][AB];           //  2,816 B
  __shared__ float w_lds[AB];               //    704 B   total 48,576 B -> 3 blocks/CU

  const int tid  = threadIdx.x;
  const int lane = tid & 63;
  const int wv   = tid >> 6;
  const int a0   = blockIdx.x * AB;
  const int q = lane >> 4, nn = lane & 15;
  const bf16x8* bfbf = (const bf16x8*)bfragG;

  // ---- issue slice 0 stage immediately (fire-and-forget) ----
  #pragma unroll
  for (int k = 0; k < 6; ++k) {
    int c = k * 256 + tid;
    if (c < 1408) {                     // 1408 = 22 waves exactly -> wave-uniform guard
      int r = c >> 3, g = c & 7;
      int row = a0 + r; if (row >= A) row = A - 1;
      const float* gp = emb + (size_t)row * 128 + (g ^ (r & 7)) * 4;
      gl_lds16(gp, (const void*)&eslice[0][c]);
    }
  }

  // per-wave B fragments for ks=0 (cols wv*32..wv*32+32) + bias/W2
  bf16x8 bbc0 = bfbf[(0 * 8 + wv * 2 + 0) * 64 + lane];
  bf16x8 bbc1 = bfbf[(0 * 8 + wv * 2 + 1) * 64 + lane];
  float b1v0, b1v1, w2v0, w2v1;
  {
    int j0 = (wv * 2) * 16 + nn, j1 = (wv * 2 + 1) * 16 + nn;
    b1v0 = b1[j0]; b1v1 = b1[j1]; w2v0 = W2[j0]; w2v1 = W2[j1];
  }

  f32x4 accA[11], accB[11];
  #pragma unroll
  for (int t = 0; t < 11; ++t) {
    accA[t] = (f32x4){0.f, 0.f, 0.f, 0.f};
    accB[t] = (f32x4){0.f, 0.f, 0.f, 0.f};
  }

  __syncthreads();                      // drains vmcnt(0): slice 0 ready

  // ---- K-streamed MFMA: ks outer (4 emb slices), tiles inner ----
  for (int ks = 0; ks < 4; ++ks) {
    const int buf = ks & 1;
    if (ks < 3) {                       // stage next slice into buf^1
      #pragma unroll
      for (int k = 0; k < 6; ++k) {
        int c = k * 256 + tid;
        if (c < 1408) {
          int r = c >> 3, g = c & 7;
          int row = a0 + r; if (row >= A) row = A - 1;
          const float* gp = emb + (size_t)row * 128 + (ks + 1) * 32 + (g ^ (r & 7)) * 4;
          gl_lds16(gp, (const void*)&eslice[buf ^ 1][c]);
        }
      }
    }
    // prefetch next B-frags (ks=3 -> loads the phys frags, used after the loop)
    bf16x8 nb0 = bfbf[((ks + 1) * 8 + wv * 2 + 0) * 64 + lane];
    bf16x8 nb1 = bfbf[((ks + 1) * 8 + wv * 2 + 1) * 64 + lane];

    #pragma unroll
    for (int t = 0; t < 11; ++t) {
      const int m = t * 16 + nn;
      const float4* rowp = &eslice[buf][m * 8];
      float4 A0 = rowp[(2 * q)     ^ (m & 7)];
      float4 A1 = rowp[(2 * q + 1) ^ (m & 7)];
      union { u32 u[4]; bf16x8 v; } af;
      af.u[0] = cvtpk(A0.x, A0.y); af.u[1] = cvtpk(A0.z, A0.w);
      af.u[2] = cvtpk(A1.x, A1.y); af.u[3] = cvtpk(A1.z, A1.w);
      accA[t] = __builtin_amdgcn_mfma_f32_16x16x32_bf16(af.v, bbc0, accA[t], 0, 0, 0);
      accB[t] = __builtin_amdgcn_mfma_f32_16x16x32_bf16(af.v, bbc1, accB[t], 0, 0, 0);
    }
    bbc0 = nb0; bbc1 = nb1;
    __syncthreads();                    // drains stage of next slice; protects buf reuse
  }

  // ---- phys pass (K=32, cols 10..31 zero), frags built in regs ----
  #pragma unroll 2
  for (int t = 0; t < 11; ++t) {
    const int m = t * 16 + nn, ga = a0 + m;
    union { u32 u[4]; bf16x8 v; } ap;
    #pragma unroll
    for (int i = 0; i < 4; ++i) {
      int c = q * 8 + i * 2;
      float2 pv = make_float2(0.f, 0.f);
      if (ga < A && c < 10) pv = *(const float2*)&phys[(size_t)ga * 10 + c];
      ap.u[i] = cvtpk(pv.x, pv.y);
    }
    accA[t] = __builtin_amdgcn_mfma_f32_16x16x32_bf16(ap.v, bbc0, accA[t], 0, 0, 0);
    accB[t] = __builtin_amdgcn_mfma_f32_16x16x32_bf16(ap.v, bbc1, accB[t], 0, 0, 0);
  }

  // ---- partial s over this wave's 32 cols; reduce across nn lanes ----
  #pragma unroll
  for (int t = 0; t < 11; ++t) {
    #pragma unroll
    for (int r = 0; r < 4; ++r) {
      float a = fast_tanh(accA[t][r] + b1v0) * w2v0
              + fast_tanh(accB[t][r] + b1v1) * w2v1;
      #pragma unroll
      for (int off = 1; off < 16; off <<= 1) a += __shfl_xor(a, off, 64);
      if (nn == 0) s_part[wv][t * 16 + q * 4 + r] = a;
    }
  }
  __syncthreads();

  // segment softmax: each wave handles 2 nucs (32-lane halves); sum 4 col partials
  {
    int seg = lane >> 5, id = lane & 31;
    int nl = wv * 2 + seg;
    int nuc = blockIdx.x * NBK + nl;
    bool act = (id < APN) && (nuc < N);
    int idx = nl * APN + id;
    float sv = act ? (s_part[0][idx] + s_part[1][idx] + s_part[2][idx] + s_part[3][idx])
                   : -3.0e38f;
    float mx = sv;
    #pragma unroll
    for (int off = 16; off; off >>= 1) mx = fmaxf(mx, __shfl_xor(mx, off, 32));
    float e = act ? __expf(sv - mx) : 0.f;
    float den = e;
    #pragma unroll
    for (int off = 16; off; off >>= 1) den += __shfl_xor(den, off, 32);
    if (id < APN) w_lds[idx] = e / den;
  }
  __syncthreads();

  // pooled[nuc] = sum_a w_a * emb[a]  (32 threads per nuc, 4 cols; emb re-read L2-hot, fp32)
  {
    int nl = tid >> 5, t32 = tid & 31;
    int nuc = blockIdx.x * NBK + nl;
    if (nuc < N) {
      float o0 = 0.f, o1 = 0.f, o2 = 0.f, o3 = 0.f;
      int base = nl * APN;
      #pragma unroll 2
      for (int a = 0; a < APN; ++a) {
        float wa = w_lds[base + a];
        float4 e = *(const float4*)&emb[(size_t)(a0 + base + a) * 128 + t32 * 4];
        o0 += wa * e.x; o1 += wa * e.y; o2 += wa * e.z; o3 += wa * e.w;
      }
      *(float4*)&pooled[(size_t)nuc * 128 + t32 * 4] = make_float4(o0, o1, o2, o3);
    }
  }
}

// ---- K3 (MFMA): combine + LN + SiLU + heads; 256 threads, 64 nucs/block ----
__global__ __launch_bounds__(256, 2) void k_combine(
    const float* __restrict__ pooled,
    const float* __restrict__ sugar_x, const float* __restrict__ phos_x,
    const float* __restrict__ sugarW, const float* __restrict__ sugarB,
    const float* __restrict__ phosW, const float* __restrict__ phosB,
    const uint4* __restrict__ combF, const float* __restrict__ combB,
    const float* __restrict__ lng, const float* __restrict__ lnb,
    const uint4* __restrict__ rotF, const float* __restrict__ rotB1,
    const float* __restrict__ rotW2, const float* __restrict__ rotB2,
    const uint4* __restrict__ trF, const float* __restrict__ trB1,
    const float* __restrict__ trW2, const float* __restrict__ trB2,
    float* __restrict__ out, int N)
{
  __shared__ u16 xbuf[64 * 392];         // 50,176 B (xt; later aliased as net[64][136])
  __shared__ u16 bsl[2][8][64][8];       // 16,384 B double-buffered comb B slices

  const int tid  = threadIdx.x;
  const int lane = tid & 63;
  const int wv   = tid >> 6;
  const int nn   = lane & 15, q = lane >> 4;
  const int nb   = blockIdx.x * 64;
  const size_t t_off  = (size_t)N * 4;
  const size_t ne_off = (size_t)N * 7;

  // ---- stage x rows as bf16 (pooled load + sugar/phos GEMV), 16 nucs per wave ----
  {
    const int j0 = lane * 2;
    float2 sBv = *(const float2*)&sugarB[j0];
    float2 pBv = *(const float2*)&phosB[j0];
    float2 swv[8], pwv[8];
    #pragma unroll
    for (int k = 0; k < 8; ++k) {
      swv[k] = *(const float2*)&sugarW[(size_t)k * 128 + j0];
      pwv[k] = *(const float2*)&phosW[(size_t)k * 128 + j0];
    }
    #pragma unroll 1
    for (int n = 0; n < 16; ++n) {
      int row = wv * 16 + n, nuc = nb + row;
      u32 up = 0, us = 0, uq = 0;
      if (nuc < N) {
        float2 pl  = ((const float2*)pooled)[(size_t)nuc * 64 + lane];
        float4 sa  = *(const float4*)&sugar_x[(size_t)nuc * 8];
        float4 sb4 = *(const float4*)&sugar_x[(size_t)nuc * 8 + 4];
        float4 pa  = *(const float4*)&phos_x[(size_t)nuc * 8];
        float4 pb4 = *(const float4*)&phos_x[(size_t)nuc * 8 + 4];
        float hs0 = sBv.x + sa.x*swv[0].x + sa.y*swv[1].x + sa.z*swv[2].x + sa.w*swv[3].x
                          + sb4.x*swv[4].x + sb4.y*swv[5].x + sb4.z*swv[6].x + sb4.w*swv[7].x;
        float hs1 = sBv.y + sa.x*swv[0].y + sa.y*swv[1].y + sa.z*swv[2].y + sa.w*swv[3].y
                          + sb4.x*swv[4].y + sb4.y*swv[5].y + sb4.z*swv[6].y + sb4.w*swv[7].y;
        float hp0 = pBv.x + pa.x*pwv[0].x + pa.y*pwv[1].x + pa.z*pwv[2].x + pa.w*pwv[3].x
                          + pb4.x*pwv[4].x + pb4.y*pwv[5].x + pb4.z*pwv[6].x + pb4.w*pwv[7].x;
        float hp1 = pBv.y + pa.x*pwv[0].y + pa.y*pwv[1].y + pa.z*pwv[2].y + pa.w*pwv[3].y
                          + pb4.x*pwv[4].y + pb4.y*pwv[5].y + pb4.z*pwv[6].y + pb4.w*pwv[7].y;
        up = pack2(pl.x, pl.y); us = pack2(hs0, hs1); uq = pack2(hp0, hp1);
      }
      *(u32*)&xbuf[row * 392 +       j0] = up;
      *(u32*)&xbuf[row * 392 + 128 + j0] = us;
      *(u32*)&xbuf[row * 392 + 256 + j0] = uq;
    }
  }
  // first comb B slice
  {
    uint4 p0 = combF[tid * 2], p1 = combF[tid * 2 + 1];
    ((uint4*)&bsl[0][0][0][0])[tid * 2]     = p0;
    ((uint4*)&bsl[0][0][0][0])[tid * 2 + 1] = p1;
  }
  __syncthreads();

  // ---- comb GEMM: z[16 x 128] per wave, K=384 (12 ks-steps) ----
  f32x4 acc[8];
  #pragma unroll
  for (int t = 0; t < 8; ++t) acc[t] = (f32x4){0.f, 0.f, 0.f, 0.f};

  const int arow = wv * 16 + nn;
  for (int ks = 0; ks < 12; ++ks) {
    const int buf = ks & 1;
    uint4 n0, n1;
    if (ks < 11) {
      n0 = combF[(ks + 1) * 512 + tid * 2];
      n1 = combF[(ks + 1) * 512 + tid * 2 + 1];
    }
    bf16x8 af = *(const bf16x8*)&xbuf[arow * 392 + ks * 32 + q * 8];
    #pragma unroll
    for (int t = 0; t < 8; ++t) {
      bf16x8 bb = *(const bf16x8*)&bsl[buf][t][lane][0];
      acc[t] = __builtin_amdgcn_mfma_f32_16x16x32_bf16(af, bb, acc[t], 0, 0, 0);
    }
    if (ks < 11) {
      ((uint4*)&bsl[buf ^ 1][0][0][0])[tid * 2]     = n0;
      ((uint4*)&bsl[buf ^ 1][0][0][0])[tid * 2 + 1] = n1;
    }
    __syncthreads();   // last iter's barrier also fences xt before net alias writes
  }

  // ---- LN + SiLU; write nuc_emb (fp32) + net (bf16, aliased over xt) ----
  {
    float gt[8], bt[8], cbv[8];
    #pragma unroll
    for (int t = 0; t < 8; ++t) {
      gt[t] = lng[t * 16 + nn]; bt[t] = lnb[t * 16 + nn]; cbv[t] = combB[t * 16 + nn];
    }
    #pragma unroll
    for (int r = 0; r < 4; ++r) {
      float z[8]; float s1 = 0.f, s2 = 0.f;
      #pragma unroll
      for (int t = 0; t < 8; ++t) {
        z[t] = acc[t][r] + cbv[t];
        s1 += z[t]; s2 += z[t] * z[t];
      }
      #pragma unroll
      for (int off = 1; off < 16; off <<= 1) {
        s1 += __shfl_xor(s1, off, 64);
        s2 += __shfl_xor(s2, off, 64);
      }
      float mu   = s1 * 0.0078125f;
      float var  = s2 * 0.0078125f - mu * mu;
      float rstd = rsqrtf(var + 1e-5f);
      int row = q * 4 + r, nuc = nb + wv * 16 + row;
      #pragma unroll
      for (int t = 0; t < 8; ++t) {
        float zn = (z[t] - mu) * rstd * gt[t] + bt[t];
        float ne = silu_f(zn);
        if (nuc < N) out[ne_off + (size_t)nuc * 128 + t * 16 + nn] = ne;
        xbuf[(wv * 16 + row) * 136 + t * 16 + nn] = f2bf(ne);
      }
    }
  }
  __syncthreads();

  // ---- rot/tr GEMMs: K=128 (4 ks-steps), B frags direct from L2 ----
  f32x4 racc[8], tacc[8];
  #pragma unroll
  for (int t = 0; t < 8; ++t) { racc[t] = (f32x4){0.f,0.f,0.f,0.f}; tacc[t] = (f32x4){0.f,0.f,0.f,0.f}; }
  #pragma unroll
  for (int ks = 0; ks < 4; ++ks) {
    bf16x8 af = *(const bf16x8*)&xbuf[arow * 136 + ks * 32 + q * 8];
    #pragma unroll
    for (int t = 0; t < 8; ++t) {
      bf16x8 rb = ((const bf16x8*)rotF)[(ks * 8 + t) * 64 + lane];
      bf16x8 tb = ((const bf16x8*)trF)[(ks * 8 + t) * 64 + lane];
      racc[t] = __builtin_amdgcn_mfma_f32_16x16x32_bf16(af, rb, racc[t], 0, 0, 0);
      tacc[t] = __builtin_amdgcn_mfma_f32_16x16x32_bf16(af, tb, tacc[t], 0, 0, 0);
    }
  }

  // ---- heads: silu + [H,4]/[H,3] projections + quat normalize ----
  {
    float rb1[8], tb1[8], twx[8], twy[8], twz[8]; float4 rw2[8];
    #pragma unroll
    for (int t = 0; t < 8; ++t) {
      int j = t * 16 + nn;
      rb1[t] = rotB1[j]; tb1[t] = trB1[j];
      rw2[t] = *(const float4*)&rotW2[(size_t)j * 4];
      twx[t] = trW2[(size_t)j * 3]; twy[t] = trW2[(size_t)j * 3 + 1]; twz[t] = trW2[(size_t)j * 3 + 2];
    }
    float qb0 = rotB2[0], qb1 = rotB2[1], qb2 = rotB2[2], qb3 = rotB2[3];
    float pb0 = trB2[0], pb1 = trB2[1], pb2 = trB2[2];
    #pragma unroll
    for (int r = 0; r < 4; ++r) {
      float q0=0.f,q1=0.f,q2=0.f,q3=0.f,p0=0.f,p1=0.f,p2=0.f;
      #pragma unroll
      for (int t = 0; t < 8; ++t) {
        float u = silu_f(racc[t][r] + rb1[t]);
        float v = silu_f(tacc[t][r] + tb1[t]);
        q0 += u * rw2[t].x; q1 += u * rw2[t].y; q2 += u * rw2[t].z; q3 += u * rw2[t].w;
        p0 += v * twx[t];   p1 += v * twy[t];   p2 += v * twz[t];
      }
      #pragma unroll
      for (int off = 1; off < 16; off <<= 1) {
        q0 += __shfl_xor(q0, off, 64); q1 += __shfl_xor(q1, off, 64);
        q2 += __shfl_xor(q2, off, 64); q3 += __shfl_xor(q3, off, 64);
        p0 += __shfl_xor(p0, off, 64); p1 += __shfl_xor(p1, off, 64);
        p2 += __shfl_xor(p2, off, 64);
      }
      int nuc = nb + wv * 16 + q * 4 + r;
      if (nn == 0 && nuc < N) {
        q0 += qb0; q1 += qb1; q2 += qb2; q3 += qb3;
        float nrm = fmaxf(sqrtf(q0*q0 + q1*q1 + q2*q2 + q3*q3), 1e-12f);
        float inv = 1.f / nrm;
        out[(size_t)nuc * 4 + 0] = q0 * inv;
        out[(size_t)nuc * 4 + 1] = q1 * inv;
        out[(size_t)nuc * 4 + 2] = q2 * inv;
        out[(size_t)nuc * 4 + 3] = q3 * inv;
        out[t_off + (size_t)nuc * 3 + 0] = p0 + pb0;
        out[t_off + (size_t)nuc * 3 + 1] = p1 + pb1;
        out[t_off + (size_t)nuc * 3 + 2] = p2 + pb2;
      }
    }
  }
}

extern "C" void kernel_launch(void* const* d_in, const int* in_sizes, int n_in,
                              void* d_out, int out_size, void* d_ws, size_t ws_size,
                              hipStream_t stream) {
  const float* phys    = (const float*)d_in[0];
  const float* emb     = (const float*)d_in[1];
  const float* sugar_x = (const float*)d_in[3];
  const float* phos_x  = (const float*)d_in[4];
  const float* sugarW  = (const float*)d_in[6];
  const float* sugarB  = (const float*)d_in[7];
  const float* phosW   = (const float*)d_in[8];
  const float* phosB   = (const float*)d_in[9];
  const float* attnW1  = (const float*)d_in[10];
  const float* attnB1  = (const float*)d_in[11];
  const float* attnW2  = (const float*)d_in[12];
  const float* combW   = (const float*)d_in[14];
  const float* combB   = (const float*)d_in[15];
  const float* lng     = (const float*)d_in[16];
  const float* lnb     = (const float*)d_in[17];
  const float* rotW1   = (const float*)d_in[18];
  const float* rotB1   = (const float*)d_in[19];
  const float* rotW2   = (const float*)d_in[20];
  const float* rotB2   = (const float*)d_in[21];
  const float* trW1    = (const float*)d_in[22];
  const float* trB1    = (const float*)d_in[23];
  const float* trW2    = (const float*)d_in[24];
  const float* trB2    = (const float*)d_in[25];

  const int A = in_sizes[2];          // 440000
  const int N = in_sizes[3] / 8;      // 20000

  char* ws = (char*)d_ws;
  u32*   bfragW1 = (u32*)ws;                    // 40,960 B
  u32*   combF   = (u32*)(ws + 40960);          // 98,304 B  [12][8][64][8] bf16 frags
  u32*   rotF    = (u32*)(ws + 139264);         // 32,768 B  [4][8][64][8]
  u32*   trF     = (u32*)(ws + 172032);         // 32,768 B  [4][8][64][8]
  float* pooled  = (float*)(ws + 204800);       // N*128*4 B

  k_prep_w1<<<40, 256, 0, stream>>>(attnW1, bfragW1);
  k_prep_frag3<<<160, 256, 0, stream>>>(combW, rotW1, trW1, combF, rotF, trF);
  k_fused<<<(N + NBK - 1) / NBK, 256, 0, stream>>>(
      phys, emb, attnB1, attnW2, (const uint4*)bfragW1, pooled, A, N);
  k_combine<<<(N + 63) / 64, 256, 0, stream>>>(
      pooled, sugar_x, phos_x, sugarW, sugarB, phosW, phosB,
      (const uint4*)combF, combB, lng, lnb,
      (const uint4*)rotF, rotB1, rotW2, rotB2,
      (const uint4*)trF, trB1, trW2, trB2,
      (float*)d_out, N);
}

// Round 4
// 434.217 us; speedup vs baseline: 1.1076x; 1.1076x over previous
//
#include <hip/hip_runtime.h>

typedef unsigned short u16;
typedef unsigned int   u32;
typedef short bf16x8 __attribute__((ext_vector_type(8)));
typedef float f32x4 __attribute__((ext_vector_type(4)));

#define APN   22
#define NBK   8            // nucleotides per k_fused block
#define AB    176          // atoms per block = 22*8 = 11 m-tiles of 16
#define EMBS  136          // embt row stride (u16): 272 B -> conflict-free-min b128 ops

__device__ __forceinline__ float bflo(u32 u){ return __uint_as_float(u << 16); }
__device__ __forceinline__ float bfhi(u32 u){ return __uint_as_float(u & 0xffff0000u); }
__device__ __forceinline__ u16 f2bf(float f){
  u32 u = __float_as_uint(f);
  u32 r = u + 0x7fffu + ((u >> 16) & 1u);
  return (u16)(r >> 16);
}
__device__ __forceinline__ u32 pack2(float a, float b){
  return (u32)f2bf(a) | ((u32)f2bf(b) << 16);
}
__device__ __forceinline__ u32 cvtpk(float lo, float hi){
  u32 d;
  asm volatile("v_cvt_pk_bf16_f32 %0, %1, %2" : "=v"(d) : "v"(lo), "v"(hi));
  return d;
}
__device__ __forceinline__ float wave_sum(float v){
  #pragma unroll
  for (int off = 32; off; off >>= 1) v += __shfl_xor(v, off, 64);
  return v;
}
__device__ __forceinline__ float fast_tanh(float x){
  float t = __expf(-2.f * x);
  return 2.f * __builtin_amdgcn_rcpf(1.f + t) - 1.f;
}
__device__ __forceinline__ float silu_f(float x){
  return x * __builtin_amdgcn_rcpf(1.f + __expf(-x));
}

// ---- prep 1: swizzle attn_W1 (fp32 [138][128]) into MFMA B-fragment layout, bf16 ----
// k-order remap: k' 0..127 -> W1 row 10+k' (emb part), 128..137 -> row k'-128 (phys), 138..159 -> 0
// layout: bfrag[ks(5)][t(8)][lane(64)][j(8)] bf16; B[k=ks*32+(lane>>4)*8+j][n=t*16+(lane&15)]
__global__ void k_prep_w1(const float* __restrict__ W1, u32* __restrict__ bfrag32)
{
  const int b = blockIdx.x;          // 0..39 = ks*8 + t
  const int ks = b >> 3, t = b & 7;
  const int e0 = threadIdx.x * 2;    // element pair
  const int lane = e0 >> 3, j = e0 & 7;
  const int n = t * 16 + (lane & 15);
  float v[2];
  #pragma unroll
  for (int i = 0; i < 2; ++i) {
    int kp = ks * 32 + ((lane >> 4) * 8) + j + i;
    float val = 0.f;
    if (kp < 128)       val = W1[(size_t)(10 + kp) * 128 + n];
    else if (kp < 138)  val = W1[(size_t)(kp - 128) * 128 + n];
    v[i] = val;
  }
  bfrag32[((size_t)(b * 64 + lane)) * 4 + (j >> 1)] = pack2(v[0], v[1]);
}

// ---- prep 2: pack comb/rot/tr W1 weights into MFMA B-fragment layout, bf16 ----
__global__ void k_prep_frag3(const float* __restrict__ combW, const float* __restrict__ rotW1,
                             const float* __restrict__ trW1,
                             u32* __restrict__ combF, u32* __restrict__ rotF, u32* __restrict__ trF)
{
  const int b = blockIdx.x;
  const float* W; u32* outp; int rel;
  if (b < 96)       { W = combW; outp = combF; rel = b; }
  else if (b < 128) { W = rotW1; outp = rotF;  rel = b - 96; }
  else              { W = trW1;  outp = trF;   rel = b - 128; }
  const int ks = rel >> 3, t = rel & 7;
  const int e0 = threadIdx.x * 2;
  const int lane = e0 >> 3, j = e0 & 7;        // j in {0,2,4,6}
  const int n = t * 16 + (lane & 15);
  const int k = ks * 32 + ((lane >> 4) * 8) + j;
  outp[((size_t)(rel * 64 + lane)) * 4 + (j >> 1)] =
      pack2(W[(size_t)k * 128 + n], W[(size_t)(k + 1) * 128 + n]);
}

// per-tile raw A-data (one lane's share): 8 float4 of emb + 4 float2 of phys
struct EBuf { float4 e[8]; float2 p[4]; };

__device__ __forceinline__ void load_tile(EBuf& b, const float* __restrict__ emb,
                                          const float* __restrict__ phys,
                                          int a0, int t, int nn, int q, int A)
{
  int ga = a0 + t * 16 + nn;
  int row = (ga < A) ? ga : (A - 1);
  const float* rp = emb + (size_t)row * 128 + q * 8;
  #pragma unroll
  for (int ks = 0; ks < 4; ++ks) {
    b.e[ks * 2]     = *(const float4*)(rp + ks * 32);
    b.e[ks * 2 + 1] = *(const float4*)(rp + ks * 32 + 4);
  }
  const float* pp = phys + (size_t)row * 10 + q * 8;
  #pragma unroll
  for (int i = 0; i < 4; ++i) {
    int c = q * 8 + 2 * i;
    b.p[i] = (c < 10) ? *(const float2*)(pp + 2 * i) : make_float2(0.f, 0.f);
  }
}

__device__ __forceinline__ void conv_tile(const EBuf& b, bf16x8 af[5])
{
  union { u32 u[4]; bf16x8 v; } w;
  #pragma unroll
  for (int ks = 0; ks < 4; ++ks) {
    w.u[0] = cvtpk(b.e[ks*2].x,   b.e[ks*2].y);
    w.u[1] = cvtpk(b.e[ks*2].z,   b.e[ks*2].w);
    w.u[2] = cvtpk(b.e[ks*2+1].x, b.e[ks*2+1].y);
    w.u[3] = cvtpk(b.e[ks*2+1].z, b.e[ks*2+1].w);
    af[ks] = w.v;
  }
  w.u[0] = cvtpk(b.p[0].x, b.p[0].y);
  w.u[1] = cvtpk(b.p[1].x, b.p[1].y);
  w.u[2] = cvtpk(b.p[2].x, b.p[2].y);
  w.u[3] = cvtpk(b.p[3].x, b.p[3].y);
  af[4] = w.v;
}

// ---- fused K1+K2 v4: tile-outer / K-inner, A direct from global (dbuf, no barriers),
// col-split B in regs, embt bf16 written as side effect (owner wave = ks slice),
// pooled from LDS (single emb fetch). ----
__global__ __launch_bounds__(256, 2) void k_fused(
    const float* __restrict__ phys, const float* __restrict__ emb,
    const float* __restrict__ b1, const float* __restrict__ W2,
    const uint4* __restrict__ bfragG,       // [5][8][64] uint4
    float* __restrict__ pooled, int A, int N)
{
  __shared__ u16 embt[AB][EMBS];            // 47,872 B
  __shared__ float s_part[4][AB];           //  2,816 B
  __shared__ float w_lds[AB];               //    704 B   total 51,392 B -> 3 blocks/CU

  const int tid  = threadIdx.x;
  const int lane = tid & 63;
  const int wv   = tid >> 6;
  const int a0   = blockIdx.x * AB;
  const int q = lane >> 4, nn = lane & 15;
  const bf16x8* bfbf = (const bf16x8*)bfragG;

  // this wave's B fragments (2 col-frags x 5 ks) resident in VGPRs
  bf16x8 bbA[5], bbB[5];
  #pragma unroll
  for (int ks = 0; ks < 5; ++ks) {
    bbA[ks] = bfbf[(ks * 8 + wv * 2 + 0) * 64 + lane];
    bbB[ks] = bfbf[(ks * 8 + wv * 2 + 1) * 64 + lane];
  }
  float b1v0, b1v1, w2v0, w2v1;
  {
    int j0 = (wv * 2) * 16 + nn, j1 = (wv * 2 + 1) * 16 + nn;
    b1v0 = b1[j0]; b1v1 = b1[j1]; w2v0 = W2[j0]; w2v1 = W2[j1];
  }

  EBuf eb[2];
  load_tile(eb[0], emb, phys, a0, 0, nn, q, A);

  // ---- 11 tiles, zero barriers: prefetch t+1 while converting/MFMA-ing t ----
  #pragma unroll
  for (int t = 0; t < 11; ++t) {
    if (t < 10) load_tile(eb[(t + 1) & 1], emb, phys, a0, t + 1, nn, q, A);

    bf16x8 af[5];
    conv_tile(eb[t & 1], af);

    // side-effect: owner wave writes its ks-slice of embt (bf16), conflict-free b128
    {
      u16* dst = &embt[t * 16 + nn][q * 8];
      if      (wv == 0) *(bf16x8*)(dst +  0) = af[0];
      else if (wv == 1) *(bf16x8*)(dst + 32) = af[1];
      else if (wv == 2) *(bf16x8*)(dst + 64) = af[2];
      else              *(bf16x8*)(dst + 96) = af[3];
    }

    f32x4 accA = (f32x4){0.f, 0.f, 0.f, 0.f};
    f32x4 accB = (f32x4){0.f, 0.f, 0.f, 0.f};
    #pragma unroll
    for (int ks = 0; ks < 5; ++ks) {
      accA = __builtin_amdgcn_mfma_f32_16x16x32_bf16(af[ks], bbA[ks], accA, 0, 0, 0);
      accB = __builtin_amdgcn_mfma_f32_16x16x32_bf16(af[ks], bbB[ks], accB, 0, 0, 0);
    }

    // partial s over this wave's 32 cols; reduce across nn lanes
    #pragma unroll
    for (int r = 0; r < 4; ++r) {
      float a = fast_tanh(accA[r] + b1v0) * w2v0
              + fast_tanh(accB[r] + b1v1) * w2v1;
      #pragma unroll
      for (int off = 1; off < 16; off <<= 1) a += __shfl_xor(a, off, 64);
      if (nn == 0) s_part[wv][t * 16 + q * 4 + r] = a;
    }
  }
  __syncthreads();

  // segment softmax: each wave handles 2 nucs (32-lane halves); sum 4 col partials
  {
    int seg = lane >> 5, id = lane & 31;
    int nl = wv * 2 + seg;
    int nuc = blockIdx.x * NBK + nl;
    bool act = (id < APN) && (nuc < N);
    int idx = nl * APN + id;
    float sv = act ? (s_part[0][idx] + s_part[1][idx] + s_part[2][idx] + s_part[3][idx])
                   : -3.0e38f;
    float mx = sv;
    #pragma unroll
    for (int off = 16; off; off >>= 1) mx = fmaxf(mx, __shfl_xor(mx, off, 32));
    float e = act ? __expf(sv - mx) : 0.f;
    float den = e;
    #pragma unroll
    for (int off = 16; off; off >>= 1) den += __shfl_xor(den, off, 32);
    if (id < APN) w_lds[idx] = e / den;
  }
  __syncthreads();

  // pooled[nuc] = sum_a w_a * emb[a]  (32 threads per nuc, 4 cols each, from LDS bf16)
  {
    int nl = tid >> 5, t32 = tid & 31;
    int nuc = blockIdx.x * NBK + nl;
    if (nuc < N) {
      float o0 = 0.f, o1 = 0.f, o2 = 0.f, o3 = 0.f;
      int base = nl * APN;
      #pragma unroll 2
      for (int a = 0; a < APN; ++a) {
        float wa = w_lds[base + a];
        uint2 u = *(const uint2*)&embt[base + a][t32 * 4];
        o0 += wa * bflo(u.x); o1 += wa * bfhi(u.x);
        o2 += wa * bflo(u.y); o3 += wa * bfhi(u.y);
      }
      *(float4*)&pooled[(size_t)nuc * 128 + t32 * 4] = make_float4(o0, o1, o2, o3);
    }
  }
}

// ---- K3 (MFMA): combine + LN + SiLU + heads; 256 threads, 64 nucs/block ----
__global__ __launch_bounds__(256, 2) void k_combine(
    const float* __restrict__ pooled,
    const float* __restrict__ sugar_x, const float* __restrict__ phos_x,
    const float* __restrict__ sugarW, const float* __restrict__ sugarB,
    const float* __restrict__ phosW, const float* __restrict__ phosB,
    const uint4* __restrict__ combF, const float* __restrict__ combB,
    const float* __restrict__ lng, const float* __restrict__ lnb,
    const uint4* __restrict__ rotF, const float* __restrict__ rotB1,
    const float* __restrict__ rotW2, const float* __restrict__ rotB2,
    const uint4* __restrict__ trF, const float* __restrict__ trB1,
    const float* __restrict__ trW2, const float* __restrict__ trB2,
    float* __restrict__ out, int N)
{
  __shared__ u16 xbuf[64 * 392];         // 50,176 B (xt; later aliased as net[64][136])
  __shared__ u16 bsl[2][8][64][8];       // 16,384 B double-buffered comb B slices

  const int tid  = threadIdx.x;
  const int lane = tid & 63;
  const int wv   = tid >> 6;
  const int nn   = lane & 15, q = lane >> 4;
  const int nb   = blockIdx.x * 64;
  const size_t t_off  = (size_t)N * 4;
  const size_t ne_off = (size_t)N * 7;

  // ---- stage x rows as bf16 (pooled load + sugar/phos GEMV), 16 nucs per wave ----
  {
    const int j0 = lane * 2;
    float2 sBv = *(const float2*)&sugarB[j0];
    float2 pBv = *(const float2*)&phosB[j0];
    float2 swv[8], pwv[8];
    #pragma unroll
    for (int k = 0; k < 8; ++k) {
      swv[k] = *(const float2*)&sugarW[(size_t)k * 128 + j0];
      pwv[k] = *(const float2*)&phosW[(size_t)k * 128 + j0];
    }
    #pragma unroll 1
    for (int n = 0; n < 16; ++n) {
      int row = wv * 16 + n, nuc = nb + row;
      u32 up = 0, us = 0, uq = 0;
      if (nuc < N) {
        float2 pl  = ((const float2*)pooled)[(size_t)nuc * 64 + lane];
        float4 sa  = *(const float4*)&sugar_x[(size_t)nuc * 8];
        float4 sb4 = *(const float4*)&sugar_x[(size_t)nuc * 8 + 4];
        float4 pa  = *(const float4*)&phos_x[(size_t)nuc * 8];
        float4 pb4 = *(const float4*)&phos_x[(size_t)nuc * 8 + 4];
        float hs0 = sBv.x + sa.x*swv[0].x + sa.y*swv[1].x + sa.z*swv[2].x + sa.w*swv[3].x
                          + sb4.x*swv[4].x + sb4.y*swv[5].x + sb4.z*swv[6].x + sb4.w*swv[7].x;
        float hs1 = sBv.y + sa.x*swv[0].y + sa.y*swv[1].y + sa.z*swv[2].y + sa.w*swv[3].y
                          + sb4.x*swv[4].y + sb4.y*swv[5].y + sb4.z*swv[6].y + sb4.w*swv[7].y;
        float hp0 = pBv.x + pa.x*pwv[0].x + pa.y*pwv[1].x + pa.z*pwv[2].x + pa.w*pwv[3].x
                          + pb4.x*pwv[4].x + pb4.y*pwv[5].x + pb4.z*pwv[6].x + pb4.w*pwv[7].x;
        float hp1 = pBv.y + pa.x*pwv[0].y + pa.y*pwv[1].y + pa.z*pwv[2].y + pa.w*pwv[3].y
                          + pb4.x*pwv[4].y + pb4.y*pwv[5].y + pb4.z*pwv[6].y + pb4.w*pwv[7].y;
        up = pack2(pl.x, pl.y); us = pack2(hs0, hs1); uq = pack2(hp0, hp1);
      }
      *(u32*)&xbuf[row * 392 +       j0] = up;
      *(u32*)&xbuf[row * 392 + 128 + j0] = us;
      *(u32*)&xbuf[row * 392 + 256 + j0] = uq;
    }
  }
  // first comb B slice
  {
    uint4 p0 = combF[tid * 2], p1 = combF[tid * 2 + 1];
    ((uint4*)&bsl[0][0][0][0])[tid * 2]     = p0;
    ((uint4*)&bsl[0][0][0][0])[tid * 2 + 1] = p1;
  }
  __syncthreads();

  // ---- comb GEMM: z[16 x 128] per wave, K=384 (12 ks-steps) ----
  f32x4 acc[8];
  #pragma unroll
  for (int t = 0; t < 8; ++t) acc[t] = (f32x4){0.f, 0.f, 0.f, 0.f};

  const int arow = wv * 16 + nn;
  for (int ks = 0; ks < 12; ++ks) {
    const int buf = ks & 1;
    uint4 n0, n1;
    if (ks < 11) {
      n0 = combF[(ks + 1) * 512 + tid * 2];
      n1 = combF[(ks + 1) * 512 + tid * 2 + 1];
    }
    bf16x8 af = *(const bf16x8*)&xbuf[arow * 392 + ks * 32 + q * 8];
    #pragma unroll
    for (int t = 0; t < 8; ++t) {
      bf16x8 bb = *(const bf16x8*)&bsl[buf][t][lane][0];
      acc[t] = __builtin_amdgcn_mfma_f32_16x16x32_bf16(af, bb, acc[t], 0, 0, 0);
    }
    if (ks < 11) {
      ((uint4*)&bsl[buf ^ 1][0][0][0])[tid * 2]     = n0;
      ((uint4*)&bsl[buf ^ 1][0][0][0])[tid * 2 + 1] = n1;
    }
    __syncthreads();   // last iter's barrier also fences xt before net alias writes
  }

  // ---- LN + SiLU; write nuc_emb (fp32) + net (bf16, aliased over xt) ----
  {
    float gt[8], bt[8], cbv[8];
    #pragma unroll
    for (int t = 0; t < 8; ++t) {
      gt[t] = lng[t * 16 + nn]; bt[t] = lnb[t * 16 + nn]; cbv[t] = combB[t * 16 + nn];
    }
    #pragma unroll
    for (int r = 0; r < 4; ++r) {
      float z[8]; float s1 = 0.f, s2 = 0.f;
      #pragma unroll
      for (int t = 0; t < 8; ++t) {
        z[t] = acc[t][r] + cbv[t];
        s1 += z[t]; s2 += z[t] * z[t];
      }
      #pragma unroll
      for (int off = 1; off < 16; off <<= 1) {
        s1 += __shfl_xor(s1, off, 64);
        s2 += __shfl_xor(s2, off, 64);
      }
      float mu   = s1 * 0.0078125f;
      float var  = s2 * 0.0078125f - mu * mu;
      float rstd = rsqrtf(var + 1e-5f);
      int row = q * 4 + r, nuc = nb + wv * 16 + row;
      #pragma unroll
      for (int t = 0; t < 8; ++t) {
        float zn = (z[t] - mu) * rstd * gt[t] + bt[t];
        float ne = silu_f(zn);
        if (nuc < N) out[ne_off + (size_t)nuc * 128 + t * 16 + nn] = ne;
        xbuf[(wv * 16 + row) * 136 + t * 16 + nn] = f2bf(ne);
      }
    }
  }
  __syncthreads();

  // ---- rot/tr GEMMs: K=128 (4 ks-steps), B frags direct from L2 ----
  f32x4 racc[8], tacc[8];
  #pragma unroll
  for (int t = 0; t < 8; ++t) { racc[t] = (f32x4){0.f,0.f,0.f,0.f}; tacc[t] = (f32x4){0.f,0.f,0.f,0.f}; }
  #pragma unroll
  for (int ks = 0; ks < 4; ++ks) {
    bf16x8 af = *(const bf16x8*)&xbuf[arow * 136 + ks * 32 + q * 8];
    #pragma unroll
    for (int t = 0; t < 8; ++t) {
      bf16x8 rb = ((const bf16x8*)rotF)[(ks * 8 + t) * 64 + lane];
      bf16x8 tb = ((const bf16x8*)trF)[(ks * 8 + t) * 64 + lane];
      racc[t] = __builtin_amdgcn_mfma_f32_16x16x32_bf16(af, rb, racc[t], 0, 0, 0);
      tacc[t] = __builtin_amdgcn_mfma_f32_16x16x32_bf16(af, tb, tacc[t], 0, 0, 0);
    }
  }

  // ---- heads: silu + [H,4]/[H,3] projections + quat normalize ----
  {
    float rb1[8], tb1[8], twx[8], twy[8], twz[8]; float4 rw2[8];
    #pragma unroll
    for (int t = 0; t < 8; ++t) {
      int j = t * 16 + nn;
      rb1[t] = rotB1[j]; tb1[t] = trB1[j];
      rw2[t] = *(const float4*)&rotW2[(size_t)j * 4];
      twx[t] = trW2[(size_t)j * 3]; twy[t] = trW2[(size_t)j * 3 + 1]; twz[t] = trW2[(size_t)j * 3 + 2];
    }
    float qb0 = rotB2[0], qb1 = rotB2[1], qb2 = rotB2[2], qb3 = rotB2[3];
    float pb0 = trB2[0], pb1 = trB2[1], pb2 = trB2[2];
    #pragma unroll
    for (int r = 0; r < 4; ++r) {
      float q0=0.f,q1=0.f,q2=0.f,q3=0.f,p0=0.f,p1=0.f,p2=0.f;
      #pragma unroll
      for (int t = 0; t < 8; ++t) {
        float u = silu_f(racc[t][r] + rb1[t]);
        float v = silu_f(tacc[t][r] + tb1[t]);
        q0 += u * rw2[t].x; q1 += u * rw2[t].y; q2 += u * rw2[t].z; q3 += u * rw2[t].w;
        p0 += v * twx[t];   p1 += v * twy[t];   p2 += v * twz[t];
      }
      #pragma unroll
      for (int off = 1; off < 16; off <<= 1) {
        q0 += __shfl_xor(q0, off, 64); q1 += __shfl_xor(q1, off, 64);
        q2 += __shfl_xor(q2, off, 64); q3 += __shfl_xor(q3, off, 64);
        p0 += __shfl_xor(p0, off, 64); p1 += __shfl_xor(p1, off, 64);
        p2 += __shfl_xor(p2, off, 64);
      }
      int nuc = nb + wv * 16 + q * 4 + r;
      if (nn == 0 && nuc < N) {
        q0 += qb0; q1 += qb1; q2 += qb2; q3 += qb3;
        float nrm = fmaxf(sqrtf(q0*q0 + q1*q1 + q2*q2 + q3*q3), 1e-12f);
        float inv = 1.f / nrm;
        out[(size_t)nuc * 4 + 0] = q0 * inv;
        out[(size_t)nuc * 4 + 1] = q1 * inv;
        out[(size_t)nuc * 4 + 2] = q2 * inv;
        out[(size_t)nuc * 4 + 3] = q3 * inv;
        out[t_off + (size_t)nuc * 3 + 0] = p0 + pb0;
        out[t_off + (size_t)nuc * 3 + 1] = p1 + pb1;
        out[t_off + (size_t)nuc * 3 + 2] = p2 + pb2;
      }
    }
  }
}

extern "C" void kernel_launch(void* const* d_in, const int* in_sizes, int n_in,
                              void* d_out, int out_size, void* d_ws, size_t ws_size,
                              hipStream_t stream) {
  const float* phys    = (const float*)d_in[0];
  const float* emb     = (const float*)d_in[1];
  const float* sugar_x = (const float*)d_in[3];
  const float* phos_x  = (const float*)d_in[4];
  const float* sugarW  = (const float*)d_in[6];
  const float* sugarB  = (const float*)d_in[7];
  const float* phosW   = (const float*)d_in[8];
  const float* phosB   = (const float*)d_in[9];
  const float* attnW1  = (const float*)d_in[10];
  const float* attnB1  = (const float*)d_in[11];
  const float* attnW2  = (const float*)d_in[12];
  const float* combW   = (const float*)d_in[14];
  const float* combB   = (const float*)d_in[15];
  const float* lng     = (const float*)d_in[16];
  const float* lnb     = (const float*)d_in[17];
  const float* rotW1   = (const float*)d_in[18];
  const float* rotB1   = (const float*)d_in[19];
  const float* rotW2   = (const float*)d_in[20];
  const float* rotB2   = (const float*)d_in[21];
  const float* trW1    = (const float*)d_in[22];
  const float* trB1    = (const float*)d_in[23];
  const float* trW2    = (const float*)d_in[24];
  const float* trB2    = (const float*)d_in[25];

  const int A = in_sizes[2];          // 440000
  const int N = in_sizes[3] / 8;      // 20000

  char* ws = (char*)d_ws;
  u32*   bfragW1 = (u32*)ws;                    // 40,960 B
  u32*   combF   = (u32*)(ws + 40960);          // 98,304 B  [12][8][64][8] bf16 frags
  u32*   rotF    = (u32*)(ws + 139264);         // 32,768 B  [4][8][64][8]
  u32*   trF     = (u32*)(ws + 172032);         // 32,768 B  [4][8][64][8]
  float* pooled  = (float*)(ws + 204800);       // N*128*4 B

  k_prep_w1<<<40, 256, 0, stream>>>(attnW1, bfragW1);
  k_prep_frag3<<<160, 256, 0, stream>>>(combW, rotW1, trW1, combF, rotF, trF);
  k_fused<<<(N + NBK - 1) / NBK, 256, 0, stream>>>(
      phys, emb, attnB1, attnW2, (const uint4*)bfragW1, pooled, A, N);
  k_combine<<<(N + 63) / 64, 256, 0, stream>>>(
      pooled, sugar_x, phos_x, sugarW, sugarB, phosW, phosB,
      (const uint4*)combF, combB, lng, lnb,
      (const uint4*)rotF, rotB1, rotW2, rotB2,
      (const uint4*)trF, trB1, trW2, trB2,
      (float*)d_out, N);
}